// Round 3
// baseline (334.611 us; speedup 1.0000x reference)
//
#include <hip/hip_runtime.h>
#include <hip/hip_bf16.h>

#define H      2048
#define IN     1408
#define NE     8
#define NTOK   2048
#define NSLOT  (NTOK*2)

typedef __attribute__((ext_vector_type(8))) short bf16x8;
typedef __attribute__((ext_vector_type(4))) float f32x4;

__device__ __forceinline__ ushort f2bf(float f) {
  unsigned u = __float_as_uint(f);
  return (ushort)((u + 0x7FFFu + ((u >> 16) & 1u)) >> 16);
}
__device__ __forceinline__ unsigned pack2(float lo, float hi) {
  return (unsigned)f2bf(lo) | ((unsigned)f2bf(hi) << 16);
}
__device__ __forceinline__ float bf2f(ushort u) {
  return __uint_as_float((unsigned)u << 16);
}

#define GLOAD_LDS16(gp, lp)                                                     \
  __builtin_amdgcn_global_load_lds(                                             \
      (const __attribute__((address_space(1))) void*)(gp),                      \
      (__attribute__((address_space(3))) void*)(lp), 16, 0, 0)

// ---------------- fused f32->bf16 convert (3 segments) + zero counts --------
__global__ __launch_bounds__(256) void cvt_all_kernel(
    const float4* __restrict__ s1, uint2* __restrict__ d1, int n1,
    const float4* __restrict__ s2, uint2* __restrict__ d2, int n2,
    const float4* __restrict__ s3, uint2* __restrict__ d3, int n3,
    int* __restrict__ counts) {
  if (blockIdx.x == 0 && threadIdx.x < NE) counts[threadIdx.x] = 0;
  int i = blockIdx.x * 256 + threadIdx.x;
  int stride = gridDim.x * 256;
  int total = n1 + n2 + n3;
  for (; i < total; i += stride) {
    const float4* s; uint2* d; int j;
    if (i < n1)            { s = s1; d = d1; j = i; }
    else if (i < n1 + n2)  { s = s2; d = d2; j = i - n1; }
    else                   { s = s3; d = d3; j = i - n1 - n2; }
    float4 v = s[j];
    uint2 o; o.x = pack2(v.x, v.y); o.y = pack2(v.z, v.w);
    d[j] = o;
  }
}

// ---------------- router: all 8 experts in parallel, 1 sync ----------------
__global__ __launch_bounds__(256) void router_kernel(
    const float* __restrict__ x, const float* __restrict__ gw,
    float* __restrict__ logits_out, int* __restrict__ counts,
    int* __restrict__ topk_idx, float* __restrict__ topk_w) {
  int n = blockIdx.x;
  __shared__ float xs[H];
  __shared__ float lg[NE];
  const float* xr = x + (size_t)n * H;
  for (int i = threadIdx.x; i < H / 4; i += 256)
    ((float4*)xs)[i] = ((const float4*)xr)[i];
  __syncthreads();
  int e = threadIdx.x >> 5;          // 8 groups of 32 lanes
  int l32 = threadIdx.x & 31;
  const float* w = gw + (size_t)e * H;
  float p = 0.f;
  for (int i = l32; i < H; i += 32) p += xs[i] * w[i];
#pragma unroll
  for (int o = 16; o; o >>= 1) p += __shfl_xor(p, o);
  if (l32 == 0) lg[e] = p;
  __syncthreads();
  if (threadIdx.x < NE) logits_out[(size_t)n * NE + threadIdx.x] = lg[threadIdx.x];
  if (threadIdx.x == 0) {
    int i1 = 0; float v1 = lg[0];
    for (int k = 1; k < NE; ++k) if (lg[k] > v1) { v1 = lg[k]; i1 = k; }
    int i2 = -1; float v2 = -1e30f;
    for (int k = 0; k < NE; ++k) if (k != i1 && lg[k] > v2) { v2 = lg[k]; i2 = k; }
    float ed = __expf(v2 - v1);
    topk_idx[n * 2 + 0] = i1; topk_idx[n * 2 + 1] = i2;
    topk_w[n * 2 + 0] = 1.f / (1.f + ed);
    topk_w[n * 2 + 1] = ed / (1.f + ed);
    atomicAdd(&counts[i1], 1);
    atomicAdd(&counts[i2], 1);
  }
}

// ---------------- scan (8 experts) ----------------
__global__ void scan_kernel(const int* __restrict__ counts,
                            int* __restrict__ offsets, int* __restrict__ cursors) {
  if (threadIdx.x == 0) {
    int s = 0;
    for (int e = 0; e < NE; ++e) { offsets[e] = s; cursors[e] = s; s += counts[e]; }
  }
}

// ---------------- scatter tokens to expert slots (+ inverse map) -----------
__global__ void scatter_kernel(const int* __restrict__ topk_idx,
                               const float* __restrict__ topk_w,
                               int* __restrict__ cursors,
                               int* __restrict__ slot_token, float* __restrict__ slot_w,
                               int* __restrict__ tok2slot) {
  int n = blockIdx.x * 256 + threadIdx.x;
  if (n < NTOK) {
    for (int k = 0; k < 2; ++k) {
      int e = topk_idx[n * 2 + k];
      int s = atomicAdd(&cursors[e], 1);
      slot_token[s] = n;
      slot_w[s] = topk_w[n * 2 + k];
      tok2slot[n * 2 + k] = s;
    }
  }
}

// Fragment read from linear LDS tile [rows][64 bf16] with slot-XOR swizzle.
__device__ __forceinline__ bf16x8 read_frag(const ushort* lds, int row, int kk, int lane) {
  int slot = (kk * 4 + (lane >> 4)) ^ (row & 7);
  return *(const bf16x8*)(lds + row * 64 + slot * 8);
}

// ---------------- GEMM1: act = silu(x@Wg^T) * (x@Wu^T), bf16 ----------------
// tile: 128 slots x (64 gate + 64 up), BK=64, double-buffered, 1 barrier/K-step
__global__ __launch_bounds__(256) void gemm1_kernel(
    const ushort* __restrict__ xb, const ushort* __restrict__ gupb,
    const int* __restrict__ offsets, const int* __restrict__ counts,
    const int* __restrict__ slot_token, ushort* __restrict__ act) {
  int e = blockIdx.z, mt = blockIdx.y, nt = blockIdx.x;
  int cnt = counts[e];
  if (mt * 128 >= cnt) return;
  int off = offsets[e];
  __shared__ ushort As[2][128 * 64], Bg[2][64 * 64], Bu[2][64 * 64];
  int tid = threadIdx.x, lane = tid & 63, wid = tid >> 6;
  int q = tid & 7;

  const ushort* aSrc[4];
#pragma unroll
  for (int it = 0; it < 4; ++it) {
    int row = (it * 256 + tid) >> 3;
    int grow = mt * 128 + row; if (grow >= cnt) grow = cnt - 1;
    int token = slot_token[off + grow];
    aSrc[it] = xb + (size_t)token * H + (size_t)((q ^ (row & 7)) * 8);
  }
  const ushort *gSrc[2], *uSrc[2];
#pragma unroll
  for (int it = 0; it < 2; ++it) {
    int row = (it * 256 + tid) >> 3;
    gSrc[it] = gupb + ((size_t)e * (2 * IN) + nt * 64 + row) * H + (size_t)((q ^ (row & 7)) * 8);
    uSrc[it] = gupb + ((size_t)e * (2 * IN) + IN + nt * 64 + row) * H + (size_t)((q ^ (row & 7)) * 8);
  }

  f32x4 zz = {0.f, 0.f, 0.f, 0.f};
  f32x4 accg[2][4], accu[2][4];
#pragma unroll
  for (int mi = 0; mi < 2; ++mi)
#pragma unroll
    for (int ni = 0; ni < 4; ++ni) { accg[mi][ni] = zz; accu[mi][ni] = zz; }

#define STAGE1(buf, k0)                                                     \
  {                                                                         \
    _Pragma("unroll")                                                       \
    for (int it = 0; it < 4; ++it)                                          \
      GLOAD_LDS16(aSrc[it] + (k0), &As[buf][it * 2048 + tid * 8]);          \
    _Pragma("unroll")                                                       \
    for (int it = 0; it < 2; ++it) {                                        \
      GLOAD_LDS16(gSrc[it] + (k0), &Bg[buf][it * 2048 + tid * 8]);          \
      GLOAD_LDS16(uSrc[it] + (k0), &Bu[buf][it * 2048 + tid * 8]);          \
    }                                                                       \
  }

  STAGE1(0, 0);
  __syncthreads();
  int cur = 0;
  for (int k = 0; k < H / 64; ++k) {
    if (k + 1 < H / 64) STAGE1(cur ^ 1, (k + 1) * 64);
#pragma unroll
    for (int kk = 0; kk < 2; ++kk) {
      bf16x8 af[2], bg[4], bu[4];
#pragma unroll
      for (int mi = 0; mi < 2; ++mi)
        af[mi] = read_frag(As[cur], wid * 32 + mi * 16 + (lane & 15), kk, lane);
#pragma unroll
      for (int ni = 0; ni < 4; ++ni) {
        bg[ni] = read_frag(Bg[cur], ni * 16 + (lane & 15), kk, lane);
        bu[ni] = read_frag(Bu[cur], ni * 16 + (lane & 15), kk, lane);
      }
#pragma unroll
      for (int mi = 0; mi < 2; ++mi)
#pragma unroll
        for (int ni = 0; ni < 4; ++ni) {
          accg[mi][ni] = __builtin_amdgcn_mfma_f32_16x16x32_bf16(af[mi], bg[ni], accg[mi][ni], 0, 0, 0);
          accu[mi][ni] = __builtin_amdgcn_mfma_f32_16x16x32_bf16(af[mi], bu[ni], accu[mi][ni], 0, 0, 0);
        }
    }
    __syncthreads();
    cur ^= 1;
  }

  int rbase = mt * 128 + wid * 32 + ((lane >> 4) << 2);
  int cbase = nt * 64 + (lane & 15);
#pragma unroll
  for (int mi = 0; mi < 2; ++mi)
#pragma unroll
    for (int r = 0; r < 4; ++r) {
      int mrow = rbase + mi * 16 + r;
      if (mrow < cnt) {
        size_t rowo = (size_t)(off + mrow) * IN;
#pragma unroll
        for (int ni = 0; ni < 4; ++ni) {
          float g = accg[mi][ni][r], u = accu[mi][ni][r];
          float a = g / (1.f + __expf(-g)) * u;
          act[rowo + cbase + ni * 16] = f2bf(a);
        }
      }
    }
}

// ---------------- GEMM2: eo[slot] = w * (act @ Wd^T), bf16 ----------------
// tile: 128 slots x 128 H-cols, BK=64, double-buffered, 1 barrier/K-step
__global__ __launch_bounds__(256) void gemm2_kernel(
    const ushort* __restrict__ act, const ushort* __restrict__ downb,
    const int* __restrict__ offsets, const int* __restrict__ counts,
    const float* __restrict__ slot_w, ushort* __restrict__ eo) {
  int e = blockIdx.z, mt = blockIdx.y, nt = blockIdx.x;
  int cnt = counts[e];
  if (mt * 128 >= cnt) return;
  int off = offsets[e];
  __shared__ ushort As[2][128 * 64], Bs[2][128 * 64];
  int tid = threadIdx.x, lane = tid & 63, wid = tid >> 6;
  int q = tid & 7;

  const ushort* aSrc[4];
#pragma unroll
  for (int it = 0; it < 4; ++it) {
    int row = (it * 256 + tid) >> 3;
    int grow = mt * 128 + row; if (grow >= cnt) grow = cnt - 1;
    aSrc[it] = act + (size_t)(off + grow) * IN + (size_t)((q ^ (row & 7)) * 8);
  }
  const ushort* bSrc[4];
#pragma unroll
  for (int it = 0; it < 4; ++it) {
    int row = (it * 256 + tid) >> 3;
    bSrc[it] = downb + ((size_t)e * H + nt * 128 + row) * IN + (size_t)((q ^ (row & 7)) * 8);
  }

  f32x4 zz = {0.f, 0.f, 0.f, 0.f};
  f32x4 acc[2][8];
#pragma unroll
  for (int mi = 0; mi < 2; ++mi)
#pragma unroll
    for (int ni = 0; ni < 8; ++ni) acc[mi][ni] = zz;

#define STAGE2(buf, k0)                                                     \
  {                                                                         \
    _Pragma("unroll")                                                       \
    for (int it = 0; it < 4; ++it) {                                        \
      GLOAD_LDS16(aSrc[it] + (k0), &As[buf][it * 2048 + tid * 8]);          \
      GLOAD_LDS16(bSrc[it] + (k0), &Bs[buf][it * 2048 + tid * 8]);          \
    }                                                                       \
  }

  STAGE2(0, 0);
  __syncthreads();
  int cur = 0;
  for (int k = 0; k < IN / 64; ++k) {
    if (k + 1 < IN / 64) STAGE2(cur ^ 1, (k + 1) * 64);
#pragma unroll
    for (int kk = 0; kk < 2; ++kk) {
      bf16x8 af[2], bf[8];
#pragma unroll
      for (int mi = 0; mi < 2; ++mi)
        af[mi] = read_frag(As[cur], wid * 32 + mi * 16 + (lane & 15), kk, lane);
#pragma unroll
      for (int ni = 0; ni < 8; ++ni)
        bf[ni] = read_frag(Bs[cur], ni * 16 + (lane & 15), kk, lane);
#pragma unroll
      for (int mi = 0; mi < 2; ++mi)
#pragma unroll
        for (int ni = 0; ni < 8; ++ni)
          acc[mi][ni] = __builtin_amdgcn_mfma_f32_16x16x32_bf16(af[mi], bf[ni], acc[mi][ni], 0, 0, 0);
    }
    __syncthreads();
    cur ^= 1;
  }

  int rbase = mt * 128 + wid * 32 + ((lane >> 4) << 2);
  int cbase = nt * 128 + (lane & 15);
#pragma unroll
  for (int mi = 0; mi < 2; ++mi)
#pragma unroll
    for (int r = 0; r < 4; ++r) {
      int mrow = rbase + mi * 16 + r;
      if (mrow < cnt) {
        int slot = off + mrow;
        float w = slot_w[slot];
#pragma unroll
        for (int ni = 0; ni < 8; ++ni)
          eo[(size_t)slot * H + cbase + ni * 16] = f2bf(w * acc[mi][ni][r]);
      }
    }
}

// ---------------- gather: out[n] = eo[slot0] + eo[slot1] ----------------
__global__ __launch_bounds__(256) void gather_kernel(
    const ushort* __restrict__ eo, const int* __restrict__ tok2slot,
    float* __restrict__ outF) {
  int idx = blockIdx.x * 256 + threadIdx.x;   // NTOK * H/8 threads
  int token = idx >> 8;                       // H/8 = 256
  int j = idx & 255;
  int s0 = tok2slot[token * 2 + 0];
  int s1 = tok2slot[token * 2 + 1];
  uint4 a = *(const uint4*)(eo + (size_t)s0 * H + j * 8);
  uint4 b = *(const uint4*)(eo + (size_t)s1 * H + j * 8);
  float4 o0, o1;
  o0.x = bf2f((ushort)(a.x & 0xffff)) + bf2f((ushort)(b.x & 0xffff));
  o0.y = bf2f((ushort)(a.x >> 16))    + bf2f((ushort)(b.x >> 16));
  o0.z = bf2f((ushort)(a.y & 0xffff)) + bf2f((ushort)(b.y & 0xffff));
  o0.w = bf2f((ushort)(a.y >> 16))    + bf2f((ushort)(b.y >> 16));
  o1.x = bf2f((ushort)(a.z & 0xffff)) + bf2f((ushort)(b.z & 0xffff));
  o1.y = bf2f((ushort)(a.z >> 16))    + bf2f((ushort)(b.z >> 16));
  o1.z = bf2f((ushort)(a.w & 0xffff)) + bf2f((ushort)(b.w & 0xffff));
  o1.w = bf2f((ushort)(a.w >> 16))    + bf2f((ushort)(b.w >> 16));
  float4* op = (float4*)(outF + (size_t)token * H + j * 8);
  op[0] = o0; op[1] = o1;
}

extern "C" void kernel_launch(void* const* d_in, const int* in_sizes, int n_in,
                              void* d_out, int out_size, void* d_ws, size_t ws_size,
                              hipStream_t stream) {
  const float* x    = (const float*)d_in[0];
  const float* gw   = (const float*)d_in[1];
  const float* gup  = (const float*)d_in[2];
  const float* down = (const float*)d_in[3];
  float* outF   = (float*)d_out;
  float* logits = outF + (size_t)NTOK * H;

  char* ws = (char*)d_ws;
  size_t o = 0;
  auto alloc = [&](size_t bytes) { char* p = ws + o; o = (o + bytes + 255) & ~(size_t)255; return p; };
  int*    counts     = (int*)alloc(32);
  int*    offsets    = (int*)alloc(32);
  int*    cursors    = (int*)alloc(32);
  int*    topk_idx   = (int*)alloc((size_t)NTOK * 2 * 4);
  float*  topk_w     = (float*)alloc((size_t)NTOK * 2 * 4);
  int*    slot_token = (int*)alloc((size_t)NSLOT * 4);
  float*  slot_w     = (float*)alloc((size_t)NSLOT * 4);
  int*    tok2slot   = (int*)alloc((size_t)NTOK * 2 * 4);
  ushort* xb         = (ushort*)alloc((size_t)NTOK * H * 2);
  ushort* act        = (ushort*)alloc((size_t)NSLOT * IN * 2);
  ushort* eo         = (ushort*)alloc((size_t)NSLOT * H * 2);
  ushort* gupb       = (ushort*)alloc((size_t)NE * 2 * IN * H * 2);
  ushort* downb      = (ushort*)alloc((size_t)NE * H * IN * 2);
  if (o > ws_size) return;

  cvt_all_kernel<<<2048, 256, 0, stream>>>(
      (const float4*)gup,  (uint2*)gupb,  NE * 2 * IN * H / 4,
      (const float4*)down, (uint2*)downb, NE * H * IN / 4,
      (const float4*)x,    (uint2*)xb,    NTOK * H / 4, counts);
  router_kernel<<<NTOK, 256, 0, stream>>>(x, gw, logits, counts, topk_idx, topk_w);
  scan_kernel<<<1, 64, 0, stream>>>(counts, offsets, cursors);
  scatter_kernel<<<NTOK / 256, 256, 0, stream>>>(topk_idx, topk_w, cursors,
                                                 slot_token, slot_w, tok2slot);
  gemm1_kernel<<<dim3(IN / 64, NTOK / 128, NE), 256, 0, stream>>>(
      xb, gupb, offsets, counts, slot_token, act);
  gemm2_kernel<<<dim3(H / 128, NTOK / 128, NE), 256, 0, stream>>>(
      act, downb, offsets, counts, slot_w, eo);
  gather_kernel<<<NTOK * H / 8 / 256, 256, 0, stream>>>(eo, tok2slot, outF);
}